// Round 2
// baseline (3775.677 us; speedup 1.0000x reference)
//
#include <hip/hip_runtime.h>
#include <hip/hip_bf16.h>

#define N_DIM 4096
#define FT_DIM 512
#define H_DIM 4
#define OUT_LD (H_DIM * N_DIM)  // 16384
#define LDS_LD 132              // 128 + 4 pad (keeps 16B alignment: 132*4=528=33*16)

__device__ inline float bf2f(unsigned short u) {
    unsigned int x = ((unsigned int)u) << 16;
    return __uint_as_float(x);
}

// ---------------------------------------------------------------------------
// Kernel 1: w[h][n] = b[h] + sum_f W[h][f] * ft[f][n]
// ---------------------------------------------------------------------------
__global__ __launch_bounds__(256) void wproj_kernel(
    const float* __restrict__ ft, const float* __restrict__ W,
    const float* __restrict__ bvec, float* __restrict__ wout) {
    int n = blockIdx.x * 256 + threadIdx.x;
    float a0 = 0.f, a1 = 0.f, a2 = 0.f, a3 = 0.f;
#pragma unroll 8
    for (int f = 0; f < FT_DIM; ++f) {
        float v = ft[(size_t)f * N_DIM + n];
        a0 = fmaf(W[0 * FT_DIM + f], v, a0);
        a1 = fmaf(W[1 * FT_DIM + f], v, a1);
        a2 = fmaf(W[2 * FT_DIM + f], v, a2);
        a3 = fmaf(W[3 * FT_DIM + f], v, a3);
    }
    wout[0 * N_DIM + n] = a0 + bvec[0];
    wout[1 * N_DIM + n] = a1 + bvec[1];
    wout[2 * N_DIM + n] = a2 + bvec[2];
    wout[3 * N_DIM + n] = a3 + bvec[3];
}

// ---------------------------------------------------------------------------
// Kernel 2: one block per row i; loops all 4 heads with bias row in registers.
// a[h][i][j] = softmax_j( leaky(w[h][i]+w[h][j], 0.2) + bias[i][j] )
// ---------------------------------------------------------------------------
template <typename T>
__global__ __launch_bounds__(256) void softmax_all_kernel(
    const float* __restrict__ w, const float* __restrict__ bias,
    T* __restrict__ a) {
    const int i = blockIdx.x;
    const int t = threadIdx.x;
    __shared__ float red[8];

    // bias row held in registers across all heads (read HBM once, not 4x)
    float bj[16];
    const float4* b4 = (const float4*)(bias + (size_t)i * N_DIM);
#pragma unroll
    for (int c = 0; c < 4; ++c) {
        float4 v = b4[t + 256 * c];
        bj[c * 4 + 0] = v.x;
        bj[c * 4 + 1] = v.y;
        bj[c * 4 + 2] = v.z;
        bj[c * 4 + 3] = v.w;
    }

    for (int h = 0; h < H_DIM; ++h) {
        __syncthreads();  // protect red[] reuse across heads
        const float wi = w[h * N_DIM + i];
        const float4* w4 = (const float4*)(w + h * N_DIM);

        float l[16];
        float m = -1e30f;
#pragma unroll
        for (int c = 0; c < 4; ++c) {
            float4 wj = w4[t + 256 * c];
            float x;
            x = wi + wj.x; x = (x >= 0.f) ? x : 0.2f * x; x += bj[c * 4 + 0]; l[c * 4 + 0] = x;
            x = wi + wj.y; x = (x >= 0.f) ? x : 0.2f * x; x += bj[c * 4 + 1]; l[c * 4 + 1] = x;
            x = wi + wj.z; x = (x >= 0.f) ? x : 0.2f * x; x += bj[c * 4 + 2]; l[c * 4 + 2] = x;
            x = wi + wj.w; x = (x >= 0.f) ? x : 0.2f * x; x += bj[c * 4 + 3]; l[c * 4 + 3] = x;
            m = fmaxf(m, fmaxf(fmaxf(l[c * 4 + 0], l[c * 4 + 1]),
                               fmaxf(l[c * 4 + 2], l[c * 4 + 3])));
        }
#pragma unroll
        for (int o = 32; o > 0; o >>= 1) m = fmaxf(m, __shfl_xor(m, o, 64));
        if ((t & 63) == 0) red[t >> 6] = m;
        __syncthreads();
        m = fmaxf(fmaxf(red[0], red[1]), fmaxf(red[2], red[3]));

        float p[16];
        float s = 0.f;
#pragma unroll
        for (int k = 0; k < 16; ++k) {
            float e = __expf(l[k] - m);
            p[k] = e;
            s += e;
        }
#pragma unroll
        for (int o = 32; o > 0; o >>= 1) s += __shfl_xor(s, o, 64);
        if ((t & 63) == 0) red[4 + (t >> 6)] = s;
        __syncthreads();
        s = (red[4] + red[5]) + (red[6] + red[7]);
        float inv = 1.0f / s;

        T* row = a + ((size_t)(h * N_DIM + i)) * N_DIM;
        if constexpr (sizeof(T) == 4) {
            float4* r4 = (float4*)row;
#pragma unroll
            for (int c = 0; c < 4; ++c) {
                r4[t + 256 * c] =
                    make_float4(p[c * 4 + 0] * inv, p[c * 4 + 1] * inv,
                                p[c * 4 + 2] * inv, p[c * 4 + 3] * inv);
            }
        } else {
#pragma unroll
            for (int c = 0; c < 4; ++c) {
                int j0 = (t + 256 * c) * 4;
                row[j0 + 0] = __float2bfloat16(p[c * 4 + 0] * inv);
                row[j0 + 1] = __float2bfloat16(p[c * 4 + 1] * inv);
                row[j0 + 2] = __float2bfloat16(p[c * 4 + 2] * inv);
                row[j0 + 3] = __float2bfloat16(p[c * 4 + 3] * inv);
            }
        }
    }
}

// ---------------------------------------------------------------------------
// Kernel 3: per head, C = A * A^T (symmetric). Only upper-triangular tile
// pairs (tI <= tK) are computed; the mirrored block is stored transposed.
// 128x128 tile, BK=16, 256 threads, 8x8 per thread (split 4+4).
// ---------------------------------------------------------------------------
template <typename T>
__device__ inline void stage_tile(const T* __restrict__ src,
                                  float dst[16][LDS_LD], int kt, int f) {
    int row = f >> 2;
    int kc = (f & 3) << 2;
    float x, y, z, ww;
    if constexpr (sizeof(T) == 4) {
        float4 v = *(const float4*)(src + (size_t)row * N_DIM + kt + kc);
        x = v.x; y = v.y; z = v.z; ww = v.w;
    } else {
        ushort4 u = *(const ushort4*)(src + (size_t)row * N_DIM + kt + kc);
        x = bf2f(u.x); y = bf2f(u.y); z = bf2f(u.z); ww = bf2f(u.w);
    }
    dst[kc + 0][row] = x;
    dst[kc + 1][row] = y;
    dst[kc + 2][row] = z;
    dst[kc + 3][row] = ww;
}

template <typename T>
__global__ __launch_bounds__(256) void aat_kernel(const T* __restrict__ A,
                                                  float* __restrict__ out) {
    const int h = blockIdx.y;
    // triangular decode: blockIdx.x -> (tI, tK) with tK >= tI, 32x32 tiles
    int idx = blockIdx.x;
    int tI = 0, base = 0;
    while (idx >= base + (32 - tI)) { base += (32 - tI); ++tI; }
    const int tK = tI + (idx - base);

    const int t = threadIdx.x;
    const int tx = t & 15;
    const int ty = t >> 4;

    __shared__ float Ast[16][LDS_LD];
    __shared__ float Bst[16][LDS_LD];

    const T* Ah = A + (size_t)h * N_DIM * N_DIM;
    const T* arow = Ah + (size_t)(tI * 128) * N_DIM;
    const T* brow = Ah + (size_t)(tK * 128) * N_DIM;

    float acc[8][8];
#pragma unroll
    for (int i2 = 0; i2 < 8; ++i2)
#pragma unroll
        for (int j2 = 0; j2 < 8; ++j2) acc[i2][j2] = 0.f;

    for (int kt = 0; kt < N_DIM; kt += 16) {
        __syncthreads();
        stage_tile<T>(arow, Ast, kt, t);
        stage_tile<T>(arow, Ast, kt, t + 256);
        stage_tile<T>(brow, Bst, kt, t);
        stage_tile<T>(brow, Bst, kt, t + 256);
        __syncthreads();
#pragma unroll
        for (int kk = 0; kk < 16; ++kk) {
            float av[8], bv[8];
            *(float4*)&av[0] = *(const float4*)&Ast[kk][ty * 4];
            *(float4*)&av[4] = *(const float4*)&Ast[kk][64 + ty * 4];
            *(float4*)&bv[0] = *(const float4*)&Bst[kk][tx * 4];
            *(float4*)&bv[4] = *(const float4*)&Bst[kk][64 + tx * 4];
#pragma unroll
            for (int i2 = 0; i2 < 8; ++i2)
#pragma unroll
                for (int j2 = 0; j2 < 8; ++j2)
                    acc[i2][j2] = fmaf(av[i2], bv[j2], acc[i2][j2]);
        }
    }

    // normal store: t[i][k] -> out[i][h*N + k]
    float* obase = out + (size_t)h * N_DIM + (size_t)(tI * 128) * OUT_LD +
                   (size_t)(tK * 128);
#pragma unroll
    for (int i2 = 0; i2 < 8; ++i2) {
        int r = (i2 < 4) ? (ty * 4 + i2) : (64 + ty * 4 + i2 - 4);
        float* orow = obase + (size_t)r * OUT_LD;
        *(float4*)&orow[tx * 4] =
            make_float4(acc[i2][0], acc[i2][1], acc[i2][2], acc[i2][3]);
        *(float4*)&orow[64 + tx * 4] =
            make_float4(acc[i2][4], acc[i2][5], acc[i2][6], acc[i2][7]);
    }

    // mirror store: t[k][i] = t[i][k] -> out[k][h*N + i] (skip diagonal)
    if (tI != tK) {
        float* mbase = out + (size_t)h * N_DIM + (size_t)(tK * 128) * OUT_LD +
                       (size_t)(tI * 128);
#pragma unroll
        for (int j2 = 0; j2 < 8; ++j2) {
            int rk = (j2 < 4) ? (tx * 4 + j2) : (64 + tx * 4 + j2 - 4);
            float* mrow = mbase + (size_t)rk * OUT_LD;
            *(float4*)&mrow[ty * 4] = make_float4(acc[0][j2], acc[1][j2],
                                                  acc[2][j2], acc[3][j2]);
            *(float4*)&mrow[64 + ty * 4] = make_float4(acc[4][j2], acc[5][j2],
                                                       acc[6][j2], acc[7][j2]);
        }
    }
}

// ---------------------------------------------------------------------------
extern "C" void kernel_launch(void* const* d_in, const int* in_sizes, int n_in,
                              void* d_out, int out_size, void* d_ws,
                              size_t ws_size, hipStream_t stream) {
    const float* ft = (const float*)d_in[0];    // (1, 512, 4096)
    const float* bias = (const float*)d_in[1];  // (1, 4096, 4096)
    const float* W = (const float*)d_in[2];     // (4, 512)
    const float* bvec = (const float*)d_in[3];  // (4,)
    float* out = (float*)d_out;                 // (1, 4096, 16384)

    float* wbuf = (float*)d_ws;  // 4*4096 floats = 64 KB
    char* abuf = (char*)d_ws + 65536;
    const size_t a_elems = (size_t)H_DIM * N_DIM * N_DIM;
    const size_t need_f32 = 65536 + a_elems * sizeof(float);

    wproj_kernel<<<dim3(16), dim3(256), 0, stream>>>(ft, W, bvec, wbuf);

    const int ntiles = 32 * 33 / 2;  // 528 upper-triangular tile pairs

    if (ws_size >= need_f32) {
        float* a = (float*)abuf;
        softmax_all_kernel<float>
            <<<dim3(N_DIM), dim3(256), 0, stream>>>(wbuf, bias, a);
        aat_kernel<float>
            <<<dim3(ntiles, H_DIM), dim3(256), 0, stream>>>(a, out);
    } else {
        __hip_bfloat16* a = (__hip_bfloat16*)abuf;
        softmax_all_kernel<__hip_bfloat16>
            <<<dim3(N_DIM), dim3(256), 0, stream>>>(wbuf, bias, a);
        aat_kernel<__hip_bfloat16>
            <<<dim3(ntiles, H_DIM), dim3(256), 0, stream>>>(a, out);
    }
}

// Round 3
// 1376.790 us; speedup vs baseline: 2.7424x; 2.7424x over previous
//
#include <hip/hip_runtime.h>
#include <hip/hip_bf16.h>

#define N_DIM 4096
#define FT_DIM 512
#define H_DIM 4
#define OUT_LD (H_DIM * N_DIM)  // 16384

typedef __attribute__((ext_vector_type(8))) __bf16 bf16x8;
typedef __attribute__((ext_vector_type(4))) float f32x4;
typedef unsigned int u32;
typedef unsigned short u16;

__device__ inline float bf2f(u16 u) {
    u32 x = ((u32)u) << 16;
    return __uint_as_float(x);
}
// round-to-nearest-even f32 -> bf16 bits
__device__ inline u16 f2bf_rn(float f) {
    u32 x = __float_as_uint(f);
    u32 r = x + 0x7fffu + ((x >> 16) & 1u);
    return (u16)(r >> 16);
}

__device__ inline void gload16(const void* g, void* l) {
    __builtin_amdgcn_global_load_lds(
        (const __attribute__((address_space(1))) u32*)g,
        (__attribute__((address_space(3))) u32*)l, 16, 0, 0);
}

// ---------------------------------------------------------------------------
// Kernel 1: w[h][n] = b[h] + sum_f W[h][f] * ft[f][n]
// ---------------------------------------------------------------------------
__global__ __launch_bounds__(256) void wproj_kernel(
    const float* __restrict__ ft, const float* __restrict__ W,
    const float* __restrict__ bvec, float* __restrict__ wout) {
    int n = blockIdx.x * 256 + threadIdx.x;
    float a0 = 0.f, a1 = 0.f, a2 = 0.f, a3 = 0.f;
#pragma unroll 8
    for (int f = 0; f < FT_DIM; ++f) {
        float v = ft[(size_t)f * N_DIM + n];
        a0 = fmaf(W[0 * FT_DIM + f], v, a0);
        a1 = fmaf(W[1 * FT_DIM + f], v, a1);
        a2 = fmaf(W[2 * FT_DIM + f], v, a2);
        a3 = fmaf(W[3 * FT_DIM + f], v, a3);
    }
    wout[0 * N_DIM + n] = a0 + bvec[0];
    wout[1 * N_DIM + n] = a1 + bvec[1];
    wout[2 * N_DIM + n] = a2 + bvec[2];
    wout[3 * N_DIM + n] = a3 + bvec[3];
}

// ---------------------------------------------------------------------------
// Kernel 2: one block per row i; loops all 4 heads, bias row in registers.
// Emits split-precision bf16: hi = bf16(a), lo = bf16(a - hi).
// ---------------------------------------------------------------------------
__global__ __launch_bounds__(256) void softmax_split_kernel(
    const float* __restrict__ w, const float* __restrict__ bias,
    u16* __restrict__ ahi, u16* __restrict__ alo) {
    const int i = blockIdx.x;
    const int t = threadIdx.x;
    __shared__ float red[8];

    float bj[16];
    const float4* b4 = (const float4*)(bias + (size_t)i * N_DIM);
#pragma unroll
    for (int c = 0; c < 4; ++c) {
        float4 v = b4[t + 256 * c];
        bj[c * 4 + 0] = v.x;
        bj[c * 4 + 1] = v.y;
        bj[c * 4 + 2] = v.z;
        bj[c * 4 + 3] = v.w;
    }

    for (int h = 0; h < H_DIM; ++h) {
        __syncthreads();
        const float wi = w[h * N_DIM + i];
        const float4* w4 = (const float4*)(w + h * N_DIM);

        float l[16];
        float m = -1e30f;
#pragma unroll
        for (int c = 0; c < 4; ++c) {
            float4 wj = w4[t + 256 * c];
            float x;
            x = wi + wj.x; x = (x >= 0.f) ? x : 0.2f * x; x += bj[c * 4 + 0]; l[c * 4 + 0] = x;
            x = wi + wj.y; x = (x >= 0.f) ? x : 0.2f * x; x += bj[c * 4 + 1]; l[c * 4 + 1] = x;
            x = wi + wj.z; x = (x >= 0.f) ? x : 0.2f * x; x += bj[c * 4 + 2]; l[c * 4 + 2] = x;
            x = wi + wj.w; x = (x >= 0.f) ? x : 0.2f * x; x += bj[c * 4 + 3]; l[c * 4 + 3] = x;
            m = fmaxf(m, fmaxf(fmaxf(l[c * 4 + 0], l[c * 4 + 1]),
                               fmaxf(l[c * 4 + 2], l[c * 4 + 3])));
        }
#pragma unroll
        for (int o = 32; o > 0; o >>= 1) m = fmaxf(m, __shfl_xor(m, o, 64));
        if ((t & 63) == 0) red[t >> 6] = m;
        __syncthreads();
        m = fmaxf(fmaxf(red[0], red[1]), fmaxf(red[2], red[3]));

        float p[16];
        float s = 0.f;
#pragma unroll
        for (int k = 0; k < 16; ++k) {
            float e = __expf(l[k] - m);
            p[k] = e;
            s += e;
        }
#pragma unroll
        for (int o = 32; o > 0; o >>= 1) s += __shfl_xor(s, o, 64);
        if ((t & 63) == 0) red[4 + (t >> 6)] = s;
        __syncthreads();
        s = (red[4] + red[5]) + (red[6] + red[7]);
        float inv = 1.0f / s;

        u16* hrow = ahi + ((size_t)(h * N_DIM + i)) * N_DIM;
        u16* lrow = alo + ((size_t)(h * N_DIM + i)) * N_DIM;
#pragma unroll
        for (int c = 0; c < 4; ++c) {
            int j0 = (t + 256 * c) * 4;
            ushort4 hv, lv;
            float av;
            av = p[c * 4 + 0] * inv; hv.x = f2bf_rn(av); lv.x = f2bf_rn(av - bf2f(hv.x));
            av = p[c * 4 + 1] * inv; hv.y = f2bf_rn(av); lv.y = f2bf_rn(av - bf2f(hv.y));
            av = p[c * 4 + 2] * inv; hv.z = f2bf_rn(av); lv.z = f2bf_rn(av - bf2f(hv.z));
            av = p[c * 4 + 3] * inv; hv.w = f2bf_rn(av); lv.w = f2bf_rn(av - bf2f(hv.w));
            *(ushort4*)(hrow + j0) = hv;
            *(ushort4*)(lrow + j0) = lv;
        }
    }
}

// ---------------------------------------------------------------------------
// Kernel 3 (MFMA): per head, t = a a^T via split bf16:
//   out_IK = U_I U_K^T + U_I L_K^T + L_I U_K^T   (all NT, one accumulator)
// 128x128 tile pair (triangular), BK=32, 4 waves in 2x2, each wave 64x64.
// LDS: 4 tiles [128][32] bf16 (8 KB each). global_load_lds w/ pre-swizzled
// source; ds_read_b128 with matching XOR swizzle (c16 ^= (row>>1)&3).
// ---------------------------------------------------------------------------
__global__ __launch_bounds__(256, 2) void aat_mfma_kernel(
    const u16* __restrict__ Ahi, const u16* __restrict__ Alo,
    float* __restrict__ out) {
    // XCD-chunked swizzle: 528 = 8 * 66 (exactly divisible -> bijective)
    const int bx = blockIdx.x;
    const int lin = (bx & 7) * 66 + (bx >> 3);
    // triangular decode: lin -> (tI, tK), tK >= tI, 32x32 tiles
    int idx = lin, tI = 0, base = 0;
    while (idx >= base + (32 - tI)) { base += (32 - tI); ++tI; }
    const int tK = tI + (idx - base);
    const int h = blockIdx.y;

    const int t = threadIdx.x;
    const int l = t & 63;
    const int wv = t >> 6;
    const int wr = wv >> 1, wc = wv & 1;  // 2x2 wave grid, each 64x64
    const int lr = l & 15, c16 = l >> 4;

    __shared__ __align__(16) unsigned char smem[32768];  // 4 tiles x 8 KB

    const size_t headoff = (size_t)h * N_DIM * N_DIM;
    const char* baseP[4];
    baseP[0] = (const char*)(Ahi + headoff + (size_t)(tI * 128) * N_DIM);  // U_I
    baseP[1] = (const char*)(Ahi + headoff + (size_t)(tK * 128) * N_DIM);  // U_K
    baseP[2] = (const char*)(Alo + headoff + (size_t)(tI * 128) * N_DIM);  // L_I
    baseP[3] = (const char*)(Alo + headoff + (size_t)(tK * 128) * N_DIM);  // L_K

    // staging offsets (bytes), fixed across K
    u32 goff[2], loff[2];
#pragma unroll
    for (int hh = 0; hh < 2; ++hh) {
        int chunk = hh * 256 + t;
        int row = chunk >> 2;
        int cc = (chunk & 3) ^ ((row >> 1) & 3);  // inverse-swizzled SOURCE
        goff[hh] = (u32)row * (N_DIM * 2) + (u32)cc * 16;
        loff[hh] = (u32)chunk * 16;  // linear LDS dest
    }

    // fragment LDS byte offsets (swizzled READ), fixed across K
    u32 offA[2][4], offB[2][4];
#pragma unroll
    for (int m = 0; m < 4; ++m) {
        int rowA = wr * 64 + m * 16 + lr;
        u32 oa = (u32)rowA * 64 + (u32)((c16 ^ ((rowA >> 1) & 3)) * 16);
        offA[0][m] = 0 * 8192 + oa;  // U_I
        offA[1][m] = 2 * 8192 + oa;  // L_I
        int rowB = wc * 64 + m * 16 + lr;
        u32 ob = (u32)rowB * 64 + (u32)((c16 ^ ((rowB >> 1) & 3)) * 16);
        offB[0][m] = 1 * 8192 + ob;  // U_K
        offB[1][m] = 3 * 8192 + ob;  // L_K
    }

    f32x4 acc[4][4];
#pragma unroll
    for (int m = 0; m < 4; ++m)
#pragma unroll
        for (int n = 0; n < 4; ++n) acc[m][n] = (f32x4){0.f, 0.f, 0.f, 0.f};

    for (int kt = 0; kt < N_DIM; kt += 32) {
        __syncthreads();
        const u32 ktb = (u32)kt * 2;
#pragma unroll
        for (int tt = 0; tt < 4; ++tt) {
            gload16(baseP[tt] + ktb + goff[0], smem + tt * 8192 + loff[0]);
            gload16(baseP[tt] + ktb + goff[1], smem + tt * 8192 + loff[1]);
        }
        __syncthreads();  // drains vmcnt -> LDS tiles ready

        bf16x8 aU[4], aL[4], bU[4], bL[4];
#pragma unroll
        for (int m = 0; m < 4; ++m) {
            aU[m] = *(const bf16x8*)(smem + offA[0][m]);
            aL[m] = *(const bf16x8*)(smem + offA[1][m]);
            bU[m] = *(const bf16x8*)(smem + offB[0][m]);
            bL[m] = *(const bf16x8*)(smem + offB[1][m]);
        }
#pragma unroll
        for (int m = 0; m < 4; ++m)
#pragma unroll
            for (int n = 0; n < 4; ++n) {
                acc[m][n] = __builtin_amdgcn_mfma_f32_16x16x32_bf16(
                    aU[m], bU[n], acc[m][n], 0, 0, 0);
                acc[m][n] = __builtin_amdgcn_mfma_f32_16x16x32_bf16(
                    aU[m], bL[n], acc[m][n], 0, 0, 0);
                acc[m][n] = __builtin_amdgcn_mfma_f32_16x16x32_bf16(
                    aL[m], bU[n], acc[m][n], 0, 0, 0);
            }
    }

    // C/D layout (m89): col = lane&15, row = (lane>>4)*4 + reg
    float* oh = out + (size_t)h * N_DIM;
    const int orow0 = tI * 128 + wr * 64;
    const int ocol0 = tK * 128 + wc * 64;
#pragma unroll
    for (int m = 0; m < 4; ++m)
#pragma unroll
        for (int n = 0; n < 4; ++n) {
            int r0 = orow0 + m * 16 + c16 * 4;
            int cc0 = ocol0 + n * 16 + lr;
            oh[(size_t)(r0 + 0) * OUT_LD + cc0] = acc[m][n][0];
            oh[(size_t)(r0 + 1) * OUT_LD + cc0] = acc[m][n][1];
            oh[(size_t)(r0 + 2) * OUT_LD + cc0] = acc[m][n][2];
            oh[(size_t)(r0 + 3) * OUT_LD + cc0] = acc[m][n][3];
        }

    if (tI != tK) {  // mirror store: out[k][i] = out[i][k]
#pragma unroll
        for (int m = 0; m < 4; ++m)
#pragma unroll
            for (int n = 0; n < 4; ++n) {
                int rm = tK * 128 + wc * 64 + n * 16 + lr;
                int cm = tI * 128 + wr * 64 + m * 16 + c16 * 4;
                *(f32x4*)(oh + (size_t)rm * OUT_LD + cm) = acc[m][n];
            }
    }
}

// ---------------------------------------------------------------------------
extern "C" void kernel_launch(void* const* d_in, const int* in_sizes, int n_in,
                              void* d_out, int out_size, void* d_ws,
                              size_t ws_size, hipStream_t stream) {
    const float* ft = (const float*)d_in[0];    // (1, 512, 4096)
    const float* bias = (const float*)d_in[1];  // (1, 4096, 4096)
    const float* W = (const float*)d_in[2];     // (4, 512)
    const float* bvec = (const float*)d_in[3];  // (4,)
    float* out = (float*)d_out;                 // (1, 4096, 16384)

    float* wbuf = (float*)d_ws;  // 64 KB
    const size_t a_elems = (size_t)H_DIM * N_DIM * N_DIM;
    u16* ahi = (u16*)((char*)d_ws + 65536);            // 128 MB
    u16* alo = (u16*)((char*)d_ws + 65536 + a_elems * 2);  // 128 MB
    // total need: 64 KB + 256 MB (same as the f32 path that fit in round 2)

    wproj_kernel<<<dim3(16), dim3(256), 0, stream>>>(ft, W, bvec, wbuf);
    softmax_split_kernel<<<dim3(N_DIM), dim3(256), 0, stream>>>(wbuf, bias,
                                                                ahi, alo);
    const int ntiles = 32 * 33 / 2;  // 528
    aat_mfma_kernel<<<dim3(ntiles, H_DIM), dim3(256), 0, stream>>>(ahi, alo,
                                                                   out);
}